// Round 1
// baseline (1254.124 us; speedup 1.0000x reference)
//
#include <hip/hip_runtime.h>

// Problem: B=8, C=384, Hin=Win=96, stride-2 subsample -> H=W=48, N=2304.
// qkv = W(1152x384) @ xs(384xN) per batch; 6 heads x (q,k,v) of 64 dims.
// attn = softmax(q^T k) ; out = v @ attn^T ; reshape to (8,384,48,48).

#define NTOK 2304
#define NB 8

// ---------------------------------------------------------------------------
// Kernel A: QKV projection GEMM.  qkv[bb][o][n] = sum_c W[o][c] * xs[b][c][n]
// xs[b][c][n] = x[b][c][2*(n/48)][2*(n%48)]
// Tile: 64(o) x 64(n), 256 threads, 4x4 per thread, K-tile 32.
// ---------------------------------------------------------------------------
__global__ __launch_bounds__(256) void qkv_proj_kernel(
    const float* __restrict__ x, const float* __restrict__ w,
    float* __restrict__ qkv, int b0) {
  const int nTile = blockIdx.x;  // 0..35
  const int oTile = blockIdx.y;  // 0..17
  const int bb = blockIdx.z;
  const int b = b0 + bb;

  __shared__ float As[32][68];  // [kk][oo]
  __shared__ float Bs[32][68];  // [kk][nn]

  const int tid = threadIdx.x;
  const int tx = tid & 15;   // n direction
  const int ty = tid >> 4;   // o direction
  const int oBase = oTile * 64;
  const int nBase = nTile * 64;
  const float* xb = x + (size_t)b * 384 * 96 * 96;

  float acc[4][4];
#pragma unroll
  for (int i = 0; i < 4; ++i)
#pragma unroll
    for (int j = 0; j < 4; ++j) acc[i][j] = 0.f;

  for (int c0 = 0; c0 < 384; c0 += 32) {
    __syncthreads();
    // Stage W tile: As[kk][oo] = W[oBase+oo][c0+kk]
#pragma unroll
    for (int i = 0; i < 8; ++i) {
      int idx = tid + i * 256;
      int kk = idx & 31;
      int oo = idx >> 5;
      As[kk][oo] = w[(size_t)(oBase + oo) * 384 + c0 + kk];
    }
    // Stage xs tile: Bs[kk][nn] = x[b][c0+kk][2h][2w]
#pragma unroll
    for (int i = 0; i < 8; ++i) {
      int idx = tid + i * 256;
      int nn = idx & 63;
      int kk = idx >> 6;
      int n = nBase + nn;
      int hh = n / 48;
      int wc = n - hh * 48;
      Bs[kk][nn] = xb[(size_t)(c0 + kk) * 9216 + hh * 192 + wc * 2];
    }
    __syncthreads();
#pragma unroll
    for (int kk = 0; kk < 32; ++kk) {
      float4 a4 = *(const float4*)&As[kk][ty * 4];
      float4 b4 = *(const float4*)&Bs[kk][tx * 4];
      float av[4] = {a4.x, a4.y, a4.z, a4.w};
      float bv[4] = {b4.x, b4.y, b4.z, b4.w};
#pragma unroll
      for (int i = 0; i < 4; ++i)
#pragma unroll
        for (int j = 0; j < 4; ++j) acc[i][j] = fmaf(av[i], bv[j], acc[i][j]);
    }
  }

  float* outp = qkv + (size_t)bb * 1152 * NTOK;
#pragma unroll
  for (int i = 0; i < 4; ++i) {
    float4 v4 = make_float4(acc[i][0], acc[i][1], acc[i][2], acc[i][3]);
    *(float4*)&outp[(size_t)(oBase + ty * 4 + i) * NTOK + nBase + tx * 4] = v4;
  }
}

// ---------------------------------------------------------------------------
// Kernel B: flash-style attention for one (batch, head, 64-query tile).
// q,k,v stored as [d][n] (64 x 2304) slices inside qkv[bb].
// S[r][c] = sum_d q[d][n0+r] k[d][m0+c]; online softmax over c tiles;
// O[r][d] = sum_m P[r][m] v[d][m] / l[r].
// 256 threads: tx=dim/key dir (16), ty=query dir (16), 4x4 per thread.
// LDS: Qs (resident), SP (K tile, reused for P tile), Vs (transposed V tile).
// ---------------------------------------------------------------------------
__global__ __launch_bounds__(256) void attn_kernel(
    const float* __restrict__ qkv, float* __restrict__ out, int b0) {
  const int nTile = blockIdx.x;  // query tile 0..35
  const int head = blockIdx.y;   // 0..5
  const int bb = blockIdx.z;
  const int b = b0 + bb;

  const float* qp = qkv + ((size_t)bb * 1152 + head * 192) * NTOK;
  const float* kp = qp + (size_t)64 * NTOK;
  const float* vp = qp + (size_t)128 * NTOK;
  const int n0 = nTile * 64;

  __shared__ float Qs[64][68];  // [d][r]
  __shared__ float SP[64][68];  // K tile as [d][c], then P tile as [m][r]
  __shared__ float Vs[64][68];  // [m][d]  (transposed on load)

  const int tid = threadIdx.x;
  const int tx = tid & 15;
  const int ty = tid >> 4;

  // Load resident Q tile: Qs[d][r] = q[d][n0+r]
#pragma unroll
  for (int i = 0; i < 16; ++i) {
    int idx = tid + i * 256;
    int r = idx & 63;
    int d = idx >> 6;
    Qs[d][r] = qp[(size_t)d * NTOK + n0 + r];
  }

  float m_run[4], l_run[4], o_acc[4][4];
#pragma unroll
  for (int i = 0; i < 4; ++i) {
    m_run[i] = -3.0e38f;
    l_run[i] = 0.f;
#pragma unroll
    for (int j = 0; j < 4; ++j) o_acc[i][j] = 0.f;
  }

  for (int mt = 0; mt < 36; ++mt) {
    const int m0 = mt * 64;
    __syncthreads();  // prior iter done with SP(P) and Vs
    // Stage K tile (SP[d][c]) and transposed V tile (Vs[c][d])
#pragma unroll
    for (int i = 0; i < 16; ++i) {
      int idx = tid + i * 256;
      int c = idx & 63;
      int d = idx >> 6;
      SP[d][c] = kp[(size_t)d * NTOK + m0 + c];
      Vs[c][d] = vp[(size_t)d * NTOK + m0 + c];
    }
    __syncthreads();

    // S = Q^T K  (rows = queries via ty, cols = keys via tx)
    float s[4][4];
#pragma unroll
    for (int i = 0; i < 4; ++i)
#pragma unroll
      for (int j = 0; j < 4; ++j) s[i][j] = 0.f;
#pragma unroll
    for (int kk = 0; kk < 64; ++kk) {
      float4 a4 = *(const float4*)&Qs[kk][ty * 4];
      float4 b4 = *(const float4*)&SP[kk][tx * 4];
      float av[4] = {a4.x, a4.y, a4.z, a4.w};
      float bv[4] = {b4.x, b4.y, b4.z, b4.w};
#pragma unroll
      for (int i = 0; i < 4; ++i)
#pragma unroll
        for (int j = 0; j < 4; ++j) s[i][j] = fmaf(av[i], bv[j], s[i][j]);
    }

    // Online softmax (row groups = 16 threads along tx = lane bits 0..3)
    float p[4][4];
#pragma unroll
    for (int i = 0; i < 4; ++i) {
      float rm = fmaxf(fmaxf(s[i][0], s[i][1]), fmaxf(s[i][2], s[i][3]));
      rm = fmaxf(rm, __shfl_xor(rm, 1));
      rm = fmaxf(rm, __shfl_xor(rm, 2));
      rm = fmaxf(rm, __shfl_xor(rm, 4));
      rm = fmaxf(rm, __shfl_xor(rm, 8));
      float mnew = fmaxf(m_run[i], rm);
      float scale = __expf(m_run[i] - mnew);
      float rs = 0.f;
#pragma unroll
      for (int j = 0; j < 4; ++j) {
        p[i][j] = __expf(s[i][j] - mnew);
        rs += p[i][j];
      }
      rs += __shfl_xor(rs, 1);
      rs += __shfl_xor(rs, 2);
      rs += __shfl_xor(rs, 4);
      rs += __shfl_xor(rs, 8);
      l_run[i] = l_run[i] * scale + rs;
      m_run[i] = mnew;
#pragma unroll
      for (int j = 0; j < 4; ++j) o_acc[i][j] *= scale;
    }

    __syncthreads();  // everyone done reading SP as K
    // Write P tile transposed: SP[m][r]
#pragma unroll
    for (int j = 0; j < 4; ++j) {
      float4 col = make_float4(p[0][j], p[1][j], p[2][j], p[3][j]);
      *(float4*)&SP[tx * 4 + j][ty * 4] = col;
    }
    __syncthreads();

    // O += P * V^T : o_acc[i][j] += sum_m SP[m][ty*4+i] * Vs[m][tx*4+j]
#pragma unroll
    for (int m = 0; m < 64; ++m) {
      float4 p4 = *(const float4*)&SP[m][ty * 4];
      float4 v4 = *(const float4*)&Vs[m][tx * 4];
      float pv[4] = {p4.x, p4.y, p4.z, p4.w};
      float vv[4] = {v4.x, v4.y, v4.z, v4.w};
#pragma unroll
      for (int i = 0; i < 4; ++i)
#pragma unroll
        for (int j = 0; j < 4; ++j)
          o_acc[i][j] = fmaf(pv[i], vv[j], o_acc[i][j]);
    }
  }

  // Epilogue: normalize and store. out[b][head*64+d][n], d=tx*4+j, n=n0+ty*4+i
  float inv[4];
#pragma unroll
  for (int i = 0; i < 4; ++i) inv[i] = 1.f / l_run[i];
#pragma unroll
  for (int j = 0; j < 4; ++j) {
    int d = tx * 4 + j;
    float4 v4 = make_float4(o_acc[0][j] * inv[0], o_acc[1][j] * inv[1],
                            o_acc[2][j] * inv[2], o_acc[3][j] * inv[3]);
    *(float4*)&out[((size_t)b * 384 + head * 64 + d) * NTOK + n0 + ty * 4] = v4;
  }
}

extern "C" void kernel_launch(void* const* d_in, const int* in_sizes, int n_in,
                              void* d_out, int out_size, void* d_ws,
                              size_t ws_size, hipStream_t stream) {
  const float* x = (const float*)d_in[0];    // (8,384,96,96)
  const float* w = (const float*)d_in[1];    // (1152,384)
  float* out = (float*)d_out;                // (8,384,48,48)
  float* ws = (float*)d_ws;

  const size_t perBatchBytes = (size_t)1152 * NTOK * sizeof(float);  // 10.6 MB
  int nbFit = (int)(ws_size / perBatchBytes);
  if (nbFit < 1) nbFit = 1;  // ws_size is expected to be >= 10.6 MB
  if (nbFit > NB) nbFit = NB;

  for (int b0 = 0; b0 < NB; b0 += nbFit) {
    int nb = NB - b0;
    if (nb > nbFit) nb = nbFit;
    dim3 gA(36, 18, nb);
    hipLaunchKernelGGL(qkv_proj_kernel, gA, dim3(256), 0, stream, x, w, ws, b0);
    dim3 gB(36, 6, nb);
    hipLaunchKernelGGL(attn_kernel, gB, dim3(256), 0, stream, ws, out, b0);
  }
}

// Round 2
// 457.007 us; speedup vs baseline: 2.7442x; 2.7442x over previous
//
#include <hip/hip_runtime.h>

// B=8, C=384, 96x96 stride-2 -> 48x48, N=2304 tokens.
// qkv = W(1152x384) @ xs(384xN); 6 heads x (q,k,v) of 64 dims.
// attn = softmax(q^T k); out[d][n] = sum_m v[d][m] P[n][m].

#define NTOK 2304
#define NB 8
#define QKV_F (1152 * NTOK)
#define PLANE_U16 (NTOK * 64)          // one bf16 plane (147456)
#define HEAD_U16 (5 * PLANE_U16)       // qhi,qlo,khi,klo,vhi
#define SLOT_U16 (6 * HEAD_U16)
#define SLOT_BYTES ((size_t)QKV_F * 4 + (size_t)SLOT_U16 * 2)  // 19.46 MB/batch

typedef __attribute__((ext_vector_type(8))) short bf16x8;
typedef __attribute__((ext_vector_type(4))) float f32x4;

__device__ __forceinline__ ushort f2bf(float f) {
  union { float f; uint u; } v; v.f = f;
  uint u = v.u;
  return (ushort)((u + 0x7fffu + ((u >> 16) & 1u)) >> 16);  // RNE
}
__device__ __forceinline__ float bf2f(ushort h) {
  union { uint u; float f; } v; v.u = ((uint)h) << 16; return v.f;
}

// ---------------------------------------------------------------------------
// Kernel A: fp32 QKV projection (unchanged structure, writes fp32 into slot).
// ---------------------------------------------------------------------------
__global__ __launch_bounds__(256) void qkv_proj_kernel(
    const float* __restrict__ x, const float* __restrict__ w, void* ws, int b0) {
  const int nTile = blockIdx.x, oTile = blockIdx.y, bb = blockIdx.z;
  const int b = b0 + bb;
  __shared__ float As[32][68];
  __shared__ float Bs[32][68];
  const int tid = threadIdx.x;
  const int tx = tid & 15, ty = tid >> 4;
  const int oBase = oTile * 64, nBase = nTile * 64;
  const float* xb = x + (size_t)b * 384 * 96 * 96;

  float acc[4][4];
#pragma unroll
  for (int i = 0; i < 4; ++i)
#pragma unroll
    for (int j = 0; j < 4; ++j) acc[i][j] = 0.f;

  for (int c0 = 0; c0 < 384; c0 += 32) {
    __syncthreads();
#pragma unroll
    for (int i = 0; i < 8; ++i) {
      int idx = tid + i * 256;
      int kk = idx & 31, oo = idx >> 5;
      As[kk][oo] = w[(size_t)(oBase + oo) * 384 + c0 + kk];
    }
#pragma unroll
    for (int i = 0; i < 8; ++i) {
      int idx = tid + i * 256;
      int nn = idx & 63, kk = idx >> 6;
      int n = nBase + nn;
      int hh = n / 48, wc = n - hh * 48;
      Bs[kk][nn] = xb[(size_t)(c0 + kk) * 9216 + hh * 192 + wc * 2];
    }
    __syncthreads();
#pragma unroll
    for (int kk = 0; kk < 32; ++kk) {
      float4 a4 = *(const float4*)&As[kk][ty * 4];
      float4 b4 = *(const float4*)&Bs[kk][tx * 4];
      float av[4] = {a4.x, a4.y, a4.z, a4.w};
      float bv[4] = {b4.x, b4.y, b4.z, b4.w};
#pragma unroll
      for (int i = 0; i < 4; ++i)
#pragma unroll
        for (int j = 0; j < 4; ++j) acc[i][j] = fmaf(av[i], bv[j], acc[i][j]);
    }
  }
  float* outp = (float*)((char*)ws + (size_t)bb * SLOT_BYTES);
#pragma unroll
  for (int i = 0; i < 4; ++i) {
    float4 v4 = make_float4(acc[i][0], acc[i][1], acc[i][2], acc[i][3]);
    *(float4*)&outp[(size_t)(oBase + ty * 4 + i) * NTOK + nBase + tx * 4] = v4;
  }
}

// ---------------------------------------------------------------------------
// Kernel T: transpose/convert fp32 qkv -> bf16 planes.
//   qT_hi/lo, kT_hi/lo: [n][64] per head;  v_hi: [64][n].
// ---------------------------------------------------------------------------
__global__ __launch_bounds__(256) void prep_kernel(void* ws) {
  const int t = blockIdx.x, h = blockIdx.y, bb = blockIdx.z;
  char* slot = (char*)ws + (size_t)bb * SLOT_BYTES;
  const float* qkvF = (const float*)slot;
  ushort* pb = (ushort*)(slot + (size_t)QKV_F * 4) + (size_t)h * HEAD_U16;
  const int n0 = t * 64;
  const float* src = qkvF + (size_t)(192 * h) * NTOK + n0;
  __shared__ float T[64][65];
  const int tid = threadIdx.x;
  const int dr = tid >> 2, c4 = (tid & 3) * 16;

  for (int part = 0; part < 2; ++part) {  // 0=q, 1=k
    const float* s0 = src + (size_t)(64 * part) * NTOK;
#pragma unroll
    for (int j = 0; j < 4; ++j) {
      float4 v = *(const float4*)&s0[(size_t)dr * NTOK + c4 + 4 * j];
      T[dr][c4 + 4 * j] = v.x; T[dr][c4 + 4 * j + 1] = v.y;
      T[dr][c4 + 4 * j + 2] = v.z; T[dr][c4 + 4 * j + 3] = v.w;
    }
    __syncthreads();
    const int n = tid >> 2, db = (tid & 3) * 16;
    uint hi[8], lo[8];
#pragma unroll
    for (int i = 0; i < 8; ++i) {
      float f0 = T[db + 2 * i][n], f1 = T[db + 2 * i + 1][n];
      ushort h0 = f2bf(f0), h1 = f2bf(f1);
      ushort l0 = f2bf(f0 - bf2f(h0)), l1 = f2bf(f1 - bf2f(h1));
      hi[i] = (uint)h0 | ((uint)h1 << 16);
      lo[i] = (uint)l0 | ((uint)l1 << 16);
    }
    ushort* dhi = pb + (size_t)(2 * part) * PLANE_U16 + (size_t)(n0 + n) * 64 + db;
    ushort* dlo = dhi + PLANE_U16;
    uint4 A0 = {hi[0], hi[1], hi[2], hi[3]}, A1 = {hi[4], hi[5], hi[6], hi[7]};
    uint4 B0 = {lo[0], lo[1], lo[2], lo[3]}, B1 = {lo[4], lo[5], lo[6], lo[7]};
    *(uint4*)dhi = A0; *(uint4*)(dhi + 8) = A1;
    *(uint4*)dlo = B0; *(uint4*)(dlo + 8) = B1;
    __syncthreads();
  }
  // v: straight convert, keep [d][n]
  const float* sv = src + (size_t)128 * NTOK;
  ushort* dv = pb + (size_t)4 * PLANE_U16 + (size_t)dr * NTOK + n0 + c4;
  uint hv[8];
#pragma unroll
  for (int j = 0; j < 4; ++j) {
    float4 v = *(const float4*)&sv[(size_t)dr * NTOK + c4 + 4 * j];
    hv[2 * j]     = (uint)f2bf(v.x) | ((uint)f2bf(v.y) << 16);
    hv[2 * j + 1] = (uint)f2bf(v.z) | ((uint)f2bf(v.w) << 16);
  }
  uint4 V0 = {hv[0], hv[1], hv[2], hv[3]}, V1 = {hv[4], hv[5], hv[6], hv[7]};
  *(uint4*)dv = V0; *(uint4*)(dv + 8) = V1;
}

// ---------------------------------------------------------------------------
// Kernel B: MFMA flash attention.  4 waves/block, 16 queries/wave.
// S^T[key][q] = mfma(K, Q) with bf16 split (3 terms); online softmax
// lane-local; P bounced through per-wave swizzled LDS; out^T = mfma(V, P^T).
// ---------------------------------------------------------------------------
__global__ __launch_bounds__(256) void attn_mfma_kernel(
    const void* ws, float* __restrict__ out, int b0) {
  const int qt = blockIdx.x, h = blockIdx.y, bb = blockIdx.z;
  const int b = b0 + bb;
  const char* slot = (const char*)ws + (size_t)bb * SLOT_BYTES;
  const ushort* base = (const ushort*)(slot + (size_t)QKV_F * 4) + (size_t)h * HEAD_U16;
  const ushort* qhiP = base;
  const ushort* qloP = base + PLANE_U16;
  const ushort* khiP = base + 2 * (size_t)PLANE_U16;
  const ushort* kloP = base + 3 * (size_t)PLANE_U16;
  const ushort* vhiP = base + 4 * (size_t)PLANE_U16;
  const int n0 = qt * 64;

  __shared__ __align__(16) ushort Khi[64 * 64];
  __shared__ __align__(16) ushort Klo[64 * 64];
  __shared__ __align__(16) ushort Vh[64 * 64];
  __shared__ __align__(16) ushort Pw[4][16 * 64];

  const int tid = threadIdx.x;
  const int w = tid >> 6;
  const int l = tid & 63;
  const int lq = l & 15;   // query column within fragment
  const int lh = l >> 4;   // 0..3

  // Q fragments (register-resident for the whole block)
  bf16x8 qh[2], ql[2];
  {
    const int qrow = n0 + 16 * w + lq;
    const ushort* qr = qhiP + (size_t)qrow * 64 + 8 * lh;
    const ushort* qr2 = qloP + (size_t)qrow * 64 + 8 * lh;
    qh[0] = *(const bf16x8*)(qr);
    qh[1] = *(const bf16x8*)(qr + 32);
    ql[0] = *(const bf16x8*)(qr2);
    ql[1] = *(const bf16x8*)(qr2 + 32);
  }

  f32x4 oac[4];
#pragma unroll
  for (int i = 0; i < 4; ++i) oac[i] = (f32x4){0.f, 0.f, 0.f, 0.f};
  float m_run = -3.0e38f, l_run = 0.f;

  for (int mt = 0; mt < 36; ++mt) {
    const int m0 = mt * 64;
    __syncthreads();
    // Stage K_hi, K_lo ([key][d]) and V_hi ([d][key]) with XOR swizzle.
#pragma unroll
    for (int i = 0; i < 6; ++i) {
      int f = tid + 256 * i;         // 0..1535
      int plane = f >> 9;
      int idx = f & 511;
      int row = idx >> 3, g = idx & 7;
      const ushort* sp;
      ushort* dp;
      if (plane == 0)      { sp = khiP + (size_t)(m0 + row) * 64 + 8 * g; dp = Khi; }
      else if (plane == 1) { sp = kloP + (size_t)(m0 + row) * 64 + 8 * g; dp = Klo; }
      else                 { sp = vhiP + (size_t)row * NTOK + m0 + 8 * g; dp = Vh; }
      uint4 v = *(const uint4*)sp;
      *(uint4*)&dp[row * 64 + 8 * (g ^ (row & 7))] = v;
    }
    __syncthreads();

    // S^T = K (A) x Q (B), split-bf16: hi*hi + hi*lo + lo*hi
    f32x4 st[4];
#pragma unroll
    for (int f = 0; f < 4; ++f) st[f] = (f32x4){0.f, 0.f, 0.f, 0.f};
#pragma unroll
    for (int f = 0; f < 4; ++f) {
#pragma unroll
      for (int s = 0; s < 2; ++s) {
        const int row = 16 * f + lq;
        const int g = 4 * s + lh;
        const int off = row * 64 + 8 * (g ^ (row & 7));
        bf16x8 ah = *(const bf16x8*)&Khi[off];
        bf16x8 al = *(const bf16x8*)&Klo[off];
        st[f] = __builtin_amdgcn_mfma_f32_16x16x32_bf16(ah, qh[s], st[f], 0, 0, 0);
        st[f] = __builtin_amdgcn_mfma_f32_16x16x32_bf16(ah, ql[s], st[f], 0, 0, 0);
        st[f] = __builtin_amdgcn_mfma_f32_16x16x32_bf16(al, qh[s], st[f], 0, 0, 0);
      }
    }

    // Online softmax: lane holds 16 keys for query lq; partner lanes lq+16g.
    float tm = st[0][0];
#pragma unroll
    for (int f = 0; f < 4; ++f)
#pragma unroll
      for (int r = 0; r < 4; ++r) tm = fmaxf(tm, st[f][r]);
    tm = fmaxf(tm, __shfl_xor(tm, 16));
    tm = fmaxf(tm, __shfl_xor(tm, 32));
    const float mnew = fmaxf(m_run, tm);
    const float scale = __expf(m_run - mnew);
    float p[4][4];
    float ls = 0.f;
#pragma unroll
    for (int f = 0; f < 4; ++f)
#pragma unroll
      for (int r = 0; r < 4; ++r) {
        p[f][r] = __expf(st[f][r] - mnew);
        ls += p[f][r];
      }
    ls += __shfl_xor(ls, 16);
    ls += __shfl_xor(ls, 32);
    l_run = l_run * scale + ls;
    m_run = mnew;
#pragma unroll
    for (int fd = 0; fd < 4; ++fd) oac[fd] *= scale;

    // Write P (bf16) into per-wave swizzled LDS: layout P[q=16][key=64].
    ushort* pw = &Pw[w][0];
#pragma unroll
    for (int f = 0; f < 4; ++f) {
      uint u0 = (uint)f2bf(p[f][0]) | ((uint)f2bf(p[f][1]) << 16);
      uint u1 = (uint)f2bf(p[f][2]) | ((uint)f2bf(p[f][3]) << 16);
      int ui = lq * 64 + 8 * ((2 * f + (lh >> 1)) ^ (lq & 7)) + 4 * (lh & 1);
      uint2 uu; uu.x = u0; uu.y = u1;
      *(uint2*)&pw[ui] = uu;
    }
    bf16x8 pbf[2];
#pragma unroll
    for (int s = 0; s < 2; ++s)
      pbf[s] = *(const bf16x8*)&pw[lq * 64 + 8 * ((4 * s + lh) ^ (lq & 7))];

    // out^T += V (A) x P^T (B)
#pragma unroll
    for (int fd = 0; fd < 4; ++fd) {
#pragma unroll
      for (int s = 0; s < 2; ++s) {
        const int row = 16 * fd + lq;
        const int g = 4 * s + lh;
        bf16x8 av = *(const bf16x8*)&Vh[row * 64 + 8 * (g ^ (row & 7))];
        oac[fd] = __builtin_amdgcn_mfma_f32_16x16x32_bf16(av, pbf[s], oac[fd], 0, 0, 0);
      }
    }
  }

  // Epilogue: out[b][h*64 + d][n],  d = 16*fd + 4*lh + r,  n = n0 + 16*w + lq.
  const float inv = 1.f / l_run;
  const int ncol = n0 + 16 * w + lq;
#pragma unroll
  for (int fd = 0; fd < 4; ++fd)
#pragma unroll
    for (int r = 0; r < 4; ++r)
      out[((size_t)b * 384 + h * 64 + 16 * fd + 4 * lh + r) * NTOK + ncol] =
          oac[fd][r] * inv;
}

extern "C" void kernel_launch(void* const* d_in, const int* in_sizes, int n_in,
                              void* d_out, int out_size, void* d_ws,
                              size_t ws_size, hipStream_t stream) {
  const float* x = (const float*)d_in[0];
  const float* w = (const float*)d_in[1];
  float* out = (float*)d_out;

  int nbFit = (int)(ws_size / SLOT_BYTES);
  if (nbFit < 1) nbFit = 1;
  if (nbFit > NB) nbFit = NB;

  for (int b0 = 0; b0 < NB; b0 += nbFit) {
    int nb = NB - b0;
    if (nb > nbFit) nb = nbFit;
    hipLaunchKernelGGL(qkv_proj_kernel, dim3(36, 18, nb), dim3(256), 0, stream,
                       x, w, d_ws, b0);
    hipLaunchKernelGGL(prep_kernel, dim3(36, 6, nb), dim3(256), 0, stream, d_ws);
    hipLaunchKernelGGL(attn_mfma_kernel, dim3(36, 6, nb), dim3(256), 0, stream,
                       d_ws, out, b0);
  }
}

// Round 3
// 282.671 us; speedup vs baseline: 4.4367x; 1.6167x over previous
//
#include <hip/hip_runtime.h>

// B=8, C=384, 96x96 stride-2 -> 48x48, N=2304 tokens.
// qkv = W(1152x384) @ xs(384xN); 6 heads x (q,k,v) of 64 dims.
// attn = softmax(q^T k); out[d][n] = sum_m v[d][m] P[n][m].
// All matmuls on MFMA via 3-term bf16 split (hi*hi + hi*lo + lo*hi).

#define NTOK 2304
#define NB 8
#define W_U16 (1152 * 384)             // one W bf16 plane
#define XT_U16 (NTOK * 384)            // one xsT bf16 plane
#define PLANE_U16 (NTOK * 64)          // one qkv bf16 plane
#define HEAD_U16 (5 * PLANE_U16)       // qhi,qlo,khi,klo,vhi
#define SLOT_U16 (2 * XT_U16 + 6 * HEAD_U16)
#define SLOT_BYTES ((size_t)SLOT_U16 * 2)     // 12.39 MB / batch
#define WBYTES ((size_t)W_U16 * 2 * 2)        // 1.77 MB

typedef __attribute__((ext_vector_type(8))) short bf16x8;
typedef __attribute__((ext_vector_type(4))) float f32x4;

__device__ __forceinline__ ushort f2bf(float f) {
  union { float f; uint u; } v; v.f = f;
  uint u = v.u;
  return (ushort)((u + 0x7fffu + ((u >> 16) & 1u)) >> 16);  // RNE
}
__device__ __forceinline__ float bf2f(ushort h) {
  union { uint u; float f; } v; v.u = ((uint)h) << 16; return v.f;
}

// ---------------------------------------------------------------------------
// Kernel W: split W (1152x384 fp32) into hi/lo bf16 planes (same layout).
// ---------------------------------------------------------------------------
__global__ __launch_bounds__(256) void prep_w_kernel(
    const float* __restrict__ w, ushort* __restrict__ wsu) {
  const int idx4 = blockIdx.x * 256 + threadIdx.x;  // 110592 total
  float4 v = *(const float4*)&w[(size_t)idx4 * 4];
  float f[4] = {v.x, v.y, v.z, v.w};
  ushort hi[4], lo[4];
#pragma unroll
  for (int j = 0; j < 4; ++j) {
    hi[j] = f2bf(f[j]);
    lo[j] = f2bf(f[j] - bf2f(hi[j]));
  }
  uint2 uh, ul;
  uh.x = (uint)hi[0] | ((uint)hi[1] << 16); uh.y = (uint)hi[2] | ((uint)hi[3] << 16);
  ul.x = (uint)lo[0] | ((uint)lo[1] << 16); ul.y = (uint)lo[2] | ((uint)lo[3] << 16);
  *(uint2*)&wsu[(size_t)idx4 * 4] = uh;
  *(uint2*)&wsu[W_U16 + (size_t)idx4 * 4] = ul;
}

// ---------------------------------------------------------------------------
// Kernel X: subsample + transpose + split x -> xsT[n][c] hi/lo bf16.
// grid (48 hh, 6 c-chunks, nb).
// ---------------------------------------------------------------------------
__global__ __launch_bounds__(256) void prep_x_kernel(
    const float* __restrict__ x, ushort* __restrict__ wsu, int b0) {
  const int hh = blockIdx.x, cc = blockIdx.y, bb = blockIdx.z;
  const int b = b0 + bb;
  const int c0 = cc * 64;
  ushort* slot = wsu + 2 * (size_t)W_U16 + (size_t)bb * SLOT_U16;
  ushort* xthi = slot;
  ushort* xtlo = slot + XT_U16;
  const float* xb = x + ((size_t)b * 384 + c0) * 9216 + 192 * hh;

  __shared__ float T[64][49];
  const int tid = threadIdx.x;
#pragma unroll
  for (int i = 0; i < 8; ++i) {
    int idx = tid + 256 * i;          // [0,2048)
    int cl = idx >> 5, q = idx & 31;
    if (q < 24) {
      float4 v = *(const float4*)&xb[(size_t)cl * 9216 + 4 * q];
      T[cl][2 * q] = v.x;
      T[cl][2 * q + 1] = v.z;
    }
  }
  __syncthreads();
#pragma unroll
  for (int i = 0; i < 2; ++i) {
    int item = tid + 256 * i;         // [0,384)
    if (item < 384) {
      int ww = item >> 3, cg = item & 7;
      int n = hh * 48 + ww;
      uint uh[4], ul[4];
#pragma unroll
      for (int p = 0; p < 4; ++p) {
        float f0 = T[8 * cg + 2 * p][ww], f1 = T[8 * cg + 2 * p + 1][ww];
        ushort h0 = f2bf(f0), h1 = f2bf(f1);
        ushort l0 = f2bf(f0 - bf2f(h0)), l1 = f2bf(f1 - bf2f(h1));
        uh[p] = (uint)h0 | ((uint)h1 << 16);
        ul[p] = (uint)l0 | ((uint)l1 << 16);
      }
      uint4 H = {uh[0], uh[1], uh[2], uh[3]};
      uint4 L = {ul[0], ul[1], ul[2], ul[3]};
      *(uint4*)&xthi[(size_t)n * 384 + c0 + 8 * cg] = H;
      *(uint4*)&xtlo[(size_t)n * 384 + c0 + 8 * cg] = L;
    }
  }
}

// ---------------------------------------------------------------------------
// Kernel G: MFMA projection GEMM, epilogue writes bf16 planes directly.
// C[o][n] tile 64x64, K=384 in 6 steps of 64. 4 waves, wave w owns
// n-subtile 16*w..16*w+15 and all 64 o's (4 fragments).
// oTile%3: 0 -> qT hi/lo, 1 -> kT hi/lo, 2 -> v hi.
// ---------------------------------------------------------------------------
__global__ __launch_bounds__(256) void qkv_mfma_kernel(
    const ushort* __restrict__ wsu, int b0) {
  const int nT = blockIdx.x, oT = blockIdx.y, bb = blockIdx.z;
  const ushort* whi = wsu;
  const ushort* wlo = wsu + W_U16;
  const ushort* slot = wsu + 2 * (size_t)W_U16 + (size_t)bb * SLOT_U16;
  const ushort* xthi = slot;
  const ushort* xtlo = slot + XT_U16;
  const int oBase = oT * 64, nBase = nT * 64;

  __shared__ __align__(16) ushort Wh[64 * 64];
  __shared__ __align__(16) ushort Wl[64 * 64];
  __shared__ __align__(16) ushort Xh[64 * 64];
  __shared__ __align__(16) ushort Xl[64 * 64];

  const int tid = threadIdx.x;
  const int w = tid >> 6, l = tid & 63;
  const int lq = l & 15, lh = l >> 4;

  f32x4 acc[4];
#pragma unroll
  for (int f = 0; f < 4; ++f) acc[f] = (f32x4){0.f, 0.f, 0.f, 0.f};

  for (int c0 = 0; c0 < 384; c0 += 64) {
    __syncthreads();
#pragma unroll
    for (int i = 0; i < 8; ++i) {
      int f = tid + 256 * i;          // [0,2048)
      int plane = f >> 9;
      int idx = f & 511;
      int row = idx >> 3, g = idx & 7;
      const ushort* sp;
      ushort* dp;
      if (plane == 0)      { sp = whi + (size_t)(oBase + row) * 384 + c0 + 8 * g; dp = Wh; }
      else if (plane == 1) { sp = wlo + (size_t)(oBase + row) * 384 + c0 + 8 * g; dp = Wl; }
      else if (plane == 2) { sp = xthi + (size_t)(nBase + row) * 384 + c0 + 8 * g; dp = Xh; }
      else                 { sp = xtlo + (size_t)(nBase + row) * 384 + c0 + 8 * g; dp = Xl; }
      uint4 v = *(const uint4*)sp;
      *(uint4*)&dp[row * 64 + 8 * (g ^ (row & 7))] = v;
    }
    __syncthreads();
#pragma unroll
    for (int s = 0; s < 2; ++s) {
      const int nrow = 16 * w + lq;
      const int g = 4 * s + lh;
      const int noff = nrow * 64 + 8 * (g ^ (nrow & 7));
      bf16x8 xh = *(const bf16x8*)&Xh[noff];
      bf16x8 xl = *(const bf16x8*)&Xl[noff];
#pragma unroll
      for (int f = 0; f < 4; ++f) {
        const int orow = 16 * f + lq;
        const int ooff = orow * 64 + 8 * (g ^ (orow & 7));
        bf16x8 wh_ = *(const bf16x8*)&Wh[ooff];
        bf16x8 wl_ = *(const bf16x8*)&Wl[ooff];
        acc[f] = __builtin_amdgcn_mfma_f32_16x16x32_bf16(wh_, xh, acc[f], 0, 0, 0);
        acc[f] = __builtin_amdgcn_mfma_f32_16x16x32_bf16(wh_, xl, acc[f], 0, 0, 0);
        acc[f] = __builtin_amdgcn_mfma_f32_16x16x32_bf16(wl_, xh, acc[f], 0, 0, 0);
      }
    }
  }

  // Epilogue. o_local = 16*f + 4*lh + r, n = nBase + 16*w + lq.
  const int t = oT % 3, head = oT / 3;
  ushort* planes = (ushort*)slot + 2 * (size_t)XT_U16 + (size_t)head * HEAD_U16;
  const int n = nBase + 16 * w + lq;
  if (t < 2) {  // q or k: transposed [n][64] hi+lo
    ushort* phi = planes + (size_t)(2 * t) * PLANE_U16;
    ushort* plo = phi + PLANE_U16;
#pragma unroll
    for (int f = 0; f < 4; ++f) {
      ushort hi[4], lo[4];
#pragma unroll
      for (int r = 0; r < 4; ++r) {
        hi[r] = f2bf(acc[f][r]);
        lo[r] = f2bf(acc[f][r] - bf2f(hi[r]));
      }
      uint2 uh, ul;
      uh.x = (uint)hi[0] | ((uint)hi[1] << 16); uh.y = (uint)hi[2] | ((uint)hi[3] << 16);
      ul.x = (uint)lo[0] | ((uint)lo[1] << 16); ul.y = (uint)lo[2] | ((uint)lo[3] << 16);
      const int d = 16 * f + 4 * lh;
      *(uint2*)&phi[(size_t)n * 64 + d] = uh;
      *(uint2*)&plo[(size_t)n * 64 + d] = ul;
    }
  } else {  // v: [d][n] hi only
    ushort* pv = planes + 4 * (size_t)PLANE_U16;
#pragma unroll
    for (int f = 0; f < 4; ++f)
#pragma unroll
      for (int r = 0; r < 4; ++r)
        pv[(size_t)(16 * f + 4 * lh + r) * NTOK + n] = f2bf(acc[f][r]);
  }
}

// ---------------------------------------------------------------------------
// Kernel B: MFMA flash attention (unchanged from round 2, new plane base).
// ---------------------------------------------------------------------------
__global__ __launch_bounds__(256) void attn_mfma_kernel(
    const ushort* __restrict__ wsu, float* __restrict__ out, int b0) {
  const int qt = blockIdx.x, h = blockIdx.y, bb = blockIdx.z;
  const int b = b0 + bb;
  const ushort* base = wsu + 2 * (size_t)W_U16 + (size_t)bb * SLOT_U16 +
                       2 * (size_t)XT_U16 + (size_t)h * HEAD_U16;
  const ushort* qhiP = base;
  const ushort* qloP = base + PLANE_U16;
  const ushort* khiP = base + 2 * (size_t)PLANE_U16;
  const ushort* kloP = base + 3 * (size_t)PLANE_U16;
  const ushort* vhiP = base + 4 * (size_t)PLANE_U16;
  const int n0 = qt * 64;

  __shared__ __align__(16) ushort Khi[64 * 64];
  __shared__ __align__(16) ushort Klo[64 * 64];
  __shared__ __align__(16) ushort Vh[64 * 64];
  __shared__ __align__(16) ushort Pw[4][16 * 64];

  const int tid = threadIdx.x;
  const int w = tid >> 6;
  const int l = tid & 63;
  const int lq = l & 15;
  const int lh = l >> 4;

  bf16x8 qh[2], ql[2];
  {
    const int qrow = n0 + 16 * w + lq;
    const ushort* qr = qhiP + (size_t)qrow * 64 + 8 * lh;
    const ushort* qr2 = qloP + (size_t)qrow * 64 + 8 * lh;
    qh[0] = *(const bf16x8*)(qr);
    qh[1] = *(const bf16x8*)(qr + 32);
    ql[0] = *(const bf16x8*)(qr2);
    ql[1] = *(const bf16x8*)(qr2 + 32);
  }

  f32x4 oac[4];
#pragma unroll
  for (int i = 0; i < 4; ++i) oac[i] = (f32x4){0.f, 0.f, 0.f, 0.f};
  float m_run = -3.0e38f, l_run = 0.f;

  for (int mt = 0; mt < 36; ++mt) {
    const int m0 = mt * 64;
    __syncthreads();
#pragma unroll
    for (int i = 0; i < 6; ++i) {
      int f = tid + 256 * i;
      int plane = f >> 9;
      int idx = f & 511;
      int row = idx >> 3, g = idx & 7;
      const ushort* sp;
      ushort* dp;
      if (plane == 0)      { sp = khiP + (size_t)(m0 + row) * 64 + 8 * g; dp = Khi; }
      else if (plane == 1) { sp = kloP + (size_t)(m0 + row) * 64 + 8 * g; dp = Klo; }
      else                 { sp = vhiP + (size_t)row * NTOK + m0 + 8 * g; dp = Vh; }
      uint4 v = *(const uint4*)sp;
      *(uint4*)&dp[row * 64 + 8 * (g ^ (row & 7))] = v;
    }
    __syncthreads();

    f32x4 st[4];
#pragma unroll
    for (int f = 0; f < 4; ++f) st[f] = (f32x4){0.f, 0.f, 0.f, 0.f};
#pragma unroll
    for (int f = 0; f < 4; ++f) {
#pragma unroll
      for (int s = 0; s < 2; ++s) {
        const int row = 16 * f + lq;
        const int g = 4 * s + lh;
        const int off = row * 64 + 8 * (g ^ (row & 7));
        bf16x8 ah = *(const bf16x8*)&Khi[off];
        bf16x8 al = *(const bf16x8*)&Klo[off];
        st[f] = __builtin_amdgcn_mfma_f32_16x16x32_bf16(ah, qh[s], st[f], 0, 0, 0);
        st[f] = __builtin_amdgcn_mfma_f32_16x16x32_bf16(ah, ql[s], st[f], 0, 0, 0);
        st[f] = __builtin_amdgcn_mfma_f32_16x16x32_bf16(al, qh[s], st[f], 0, 0, 0);
      }
    }

    float tm = st[0][0];
#pragma unroll
    for (int f = 0; f < 4; ++f)
#pragma unroll
      for (int r = 0; r < 4; ++r) tm = fmaxf(tm, st[f][r]);
    tm = fmaxf(tm, __shfl_xor(tm, 16));
    tm = fmaxf(tm, __shfl_xor(tm, 32));
    const float mnew = fmaxf(m_run, tm);
    const float scale = __expf(m_run - mnew);
    float p[4][4];
    float ls = 0.f;
#pragma unroll
    for (int f = 0; f < 4; ++f)
#pragma unroll
      for (int r = 0; r < 4; ++r) {
        p[f][r] = __expf(st[f][r] - mnew);
        ls += p[f][r];
      }
    ls += __shfl_xor(ls, 16);
    ls += __shfl_xor(ls, 32);
    l_run = l_run * scale + ls;
    m_run = mnew;
#pragma unroll
    for (int fd = 0; fd < 4; ++fd) oac[fd] *= scale;

    ushort* pw = &Pw[w][0];
#pragma unroll
    for (int f = 0; f < 4; ++f) {
      uint u0 = (uint)f2bf(p[f][0]) | ((uint)f2bf(p[f][1]) << 16);
      uint u1 = (uint)f2bf(p[f][2]) | ((uint)f2bf(p[f][3]) << 16);
      int ui = lq * 64 + 8 * ((2 * f + (lh >> 1)) ^ (lq & 7)) + 4 * (lh & 1);
      uint2 uu; uu.x = u0; uu.y = u1;
      *(uint2*)&pw[ui] = uu;
    }
    bf16x8 pbf[2];
#pragma unroll
    for (int s = 0; s < 2; ++s)
      pbf[s] = *(const bf16x8*)&pw[lq * 64 + 8 * ((4 * s + lh) ^ (lq & 7))];

#pragma unroll
    for (int fd = 0; fd < 4; ++fd) {
#pragma unroll
      for (int s = 0; s < 2; ++s) {
        const int row = 16 * fd + lq;
        const int g = 4 * s + lh;
        bf16x8 av = *(const bf16x8*)&Vh[row * 64 + 8 * (g ^ (row & 7))];
        oac[fd] = __builtin_amdgcn_mfma_f32_16x16x32_bf16(av, pbf[s], oac[fd], 0, 0, 0);
      }
    }
  }

  const float inv = 1.f / l_run;
  const int ncol = n0 + 16 * w + lq;
#pragma unroll
  for (int fd = 0; fd < 4; ++fd)
#pragma unroll
    for (int r = 0; r < 4; ++r)
      out[((size_t)b * 384 + h * 64 + 16 * fd + 4 * lh + r) * NTOK + ncol] =
          oac[fd][r] * inv;
}

extern "C" void kernel_launch(void* const* d_in, const int* in_sizes, int n_in,
                              void* d_out, int out_size, void* d_ws,
                              size_t ws_size, hipStream_t stream) {
  const float* x = (const float*)d_in[0];
  const float* w = (const float*)d_in[1];
  float* out = (float*)d_out;
  ushort* wsu = (ushort*)d_ws;

  int nbFit = (int)((ws_size - WBYTES) / SLOT_BYTES);
  if (nbFit < 1) nbFit = 1;
  if (nbFit > NB) nbFit = NB;

  hipLaunchKernelGGL(prep_w_kernel, dim3(432), dim3(256), 0, stream, w, wsu);
  for (int b0 = 0; b0 < NB; b0 += nbFit) {
    int nb = NB - b0;
    if (nb > nbFit) nb = nbFit;
    hipLaunchKernelGGL(prep_x_kernel, dim3(48, 6, nb), dim3(256), 0, stream,
                       x, wsu, b0);
    hipLaunchKernelGGL(qkv_mfma_kernel, dim3(36, 18, nb), dim3(256), 0, stream,
                       wsu, b0);
    hipLaunchKernelGGL(attn_mfma_kernel, dim3(36, 6, nb), dim3(256), 0, stream,
                       wsu, out, b0);
  }
}

// Round 4
// 252.037 us; speedup vs baseline: 4.9759x; 1.1215x over previous
//
#include <hip/hip_runtime.h>

// B=8, C=384, 96x96 stride-2 -> 48x48, N=2304 tokens.
// qkv = W(1152x384) @ xs(384xN); 6 heads x (q,k,v) of 64 dims.
// attn = softmax(q^T k); out[d][n] = sum_m v[d][m] P[n][m].
// All matmuls on MFMA via 3-term bf16 split (hi*hi + hi*lo + lo*hi).
// Q is pre-scaled by log2(e); softmax runs in the exp2 domain.

#define NTOK 2304
#define NB 8
#define W_U16 (1152 * 384)             // one W bf16 plane
#define XT_U16 (NTOK * 384)            // one xsT bf16 plane
#define PLANE_U16 (NTOK * 64)          // one qkv bf16 plane
#define HEAD_U16 (5 * PLANE_U16)       // qhi,qlo + kv-tiles(3 planes worth)
#define SLOT_U16 (2 * XT_U16 + 6 * HEAD_U16)
#define SLOT_BYTES ((size_t)SLOT_U16 * 2)     // 12.39 MB / batch
#define WBYTES ((size_t)W_U16 * 2 * 2)        // 1.77 MB
#define LOG2E 1.4426950408889634f

typedef __attribute__((ext_vector_type(8))) short bf16x8;
typedef __attribute__((ext_vector_type(4))) float f32x4;

__device__ __forceinline__ ushort f2bf(float f) {
  union { float f; uint u; } v; v.f = f;
  uint u = v.u;
  return (ushort)((u + 0x7fffu + ((u >> 16) & 1u)) >> 16);  // RNE
}
__device__ __forceinline__ float bf2f(ushort h) {
  union { uint u; float f; } v; v.u = ((uint)h) << 16; return v.f;
}
__device__ __forceinline__ uint cvt_pk_bf16(float lo, float hi) {
  uint r;
  asm("v_cvt_pk_bf16_f32 %0, %1, %2" : "=v"(r) : "v"(lo), "v"(hi));
  return r;
}
__device__ __forceinline__ float exp2_fast(float x) {
  float r;
  asm("v_exp_f32 %0, %1" : "=v"(r) : "v"(x));
  return r;
}
__device__ __forceinline__ void gload16(const void* g, void* l) {
  __builtin_amdgcn_global_load_lds(
      (const __attribute__((address_space(1))) unsigned int*)g,
      (__attribute__((address_space(3))) unsigned int*)l, 16, 0, 0);
}

// ---------------------------------------------------------------------------
// Kernel W: split W (1152x384 fp32) into hi/lo bf16 planes (same layout).
// ---------------------------------------------------------------------------
__global__ __launch_bounds__(256) void prep_w_kernel(
    const float* __restrict__ w, ushort* __restrict__ wsu) {
  const int idx4 = blockIdx.x * 256 + threadIdx.x;  // 110592 total
  float4 v = *(const float4*)&w[(size_t)idx4 * 4];
  float f[4] = {v.x, v.y, v.z, v.w};
  ushort hi[4], lo[4];
#pragma unroll
  for (int j = 0; j < 4; ++j) {
    hi[j] = f2bf(f[j]);
    lo[j] = f2bf(f[j] - bf2f(hi[j]));
  }
  uint2 uh, ul;
  uh.x = (uint)hi[0] | ((uint)hi[1] << 16); uh.y = (uint)hi[2] | ((uint)hi[3] << 16);
  ul.x = (uint)lo[0] | ((uint)lo[1] << 16); ul.y = (uint)lo[2] | ((uint)lo[3] << 16);
  *(uint2*)&wsu[(size_t)idx4 * 4] = uh;
  *(uint2*)&wsu[W_U16 + (size_t)idx4 * 4] = ul;
}

// ---------------------------------------------------------------------------
// Kernel X: subsample + transpose + split x -> xsT[n][c] hi/lo bf16.
// ---------------------------------------------------------------------------
__global__ __launch_bounds__(256) void prep_x_kernel(
    const float* __restrict__ x, ushort* __restrict__ wsu, int b0) {
  const int hh = blockIdx.x, cc = blockIdx.y, bb = blockIdx.z;
  const int b = b0 + bb;
  const int c0 = cc * 64;
  ushort* slot = wsu + 2 * (size_t)W_U16 + (size_t)bb * SLOT_U16;
  ushort* xthi = slot;
  ushort* xtlo = slot + XT_U16;
  const float* xb = x + ((size_t)b * 384 + c0) * 9216 + 192 * hh;

  __shared__ float T[64][49];
  const int tid = threadIdx.x;
#pragma unroll
  for (int i = 0; i < 8; ++i) {
    int idx = tid + 256 * i;
    int cl = idx >> 5, q = idx & 31;
    if (q < 24) {
      float4 v = *(const float4*)&xb[(size_t)cl * 9216 + 4 * q];
      T[cl][2 * q] = v.x;
      T[cl][2 * q + 1] = v.z;
    }
  }
  __syncthreads();
#pragma unroll
  for (int i = 0; i < 2; ++i) {
    int item = tid + 256 * i;
    if (item < 384) {
      int ww = item >> 3, cg = item & 7;
      int n = hh * 48 + ww;
      uint uh[4], ul[4];
#pragma unroll
      for (int p = 0; p < 4; ++p) {
        float f0 = T[8 * cg + 2 * p][ww], f1 = T[8 * cg + 2 * p + 1][ww];
        ushort h0 = f2bf(f0), h1 = f2bf(f1);
        ushort l0 = f2bf(f0 - bf2f(h0)), l1 = f2bf(f1 - bf2f(h1));
        uh[p] = (uint)h0 | ((uint)h1 << 16);
        ul[p] = (uint)l0 | ((uint)l1 << 16);
      }
      uint4 H = {uh[0], uh[1], uh[2], uh[3]};
      uint4 L = {ul[0], ul[1], ul[2], ul[3]};
      *(uint4*)&xthi[(size_t)n * 384 + c0 + 8 * cg] = H;
      *(uint4*)&xtlo[(size_t)n * 384 + c0 + 8 * cg] = L;
    }
  }
}

// ---------------------------------------------------------------------------
// Kernel G: MFMA projection GEMM.  Epilogue writes attention-ready layouts:
//  t=0 (q): [n][64] hi/lo, values pre-scaled by log2(e)
//  t=1 (k): per-64-key swizzled tile, planes hi/lo (tile = 24 KB: Khi|Klo|V)
//  t=2 (v): same tile, plane 2, rows = d, cols = key, row-swizzled
// ---------------------------------------------------------------------------
__global__ __launch_bounds__(256) void qkv_mfma_kernel(
    const ushort* __restrict__ wsu, int b0) {
  const int nT = blockIdx.x, oT = blockIdx.y, bb = blockIdx.z;
  const ushort* whi = wsu;
  const ushort* wlo = wsu + W_U16;
  const ushort* slot = wsu + 2 * (size_t)W_U16 + (size_t)bb * SLOT_U16;
  const ushort* xthi = slot;
  const ushort* xtlo = slot + XT_U16;
  const int oBase = oT * 64, nBase = nT * 64;

  __shared__ __align__(16) ushort Wh[64 * 64];
  __shared__ __align__(16) ushort Wl[64 * 64];
  __shared__ __align__(16) ushort Xh[64 * 64];
  __shared__ __align__(16) ushort Xl[64 * 64];

  const int tid = threadIdx.x;
  const int w = tid >> 6, l = tid & 63;
  const int lq = l & 15, lh = l >> 4;

  f32x4 acc[4];
#pragma unroll
  for (int f = 0; f < 4; ++f) acc[f] = (f32x4){0.f, 0.f, 0.f, 0.f};

  for (int c0 = 0; c0 < 384; c0 += 64) {
    __syncthreads();
#pragma unroll
    for (int i = 0; i < 8; ++i) {
      int f = tid + 256 * i;
      int plane = f >> 9;
      int idx = f & 511;
      int row = idx >> 3, g = idx & 7;
      const ushort* sp;
      ushort* dp;
      if (plane == 0)      { sp = whi + (size_t)(oBase + row) * 384 + c0 + 8 * g; dp = Wh; }
      else if (plane == 1) { sp = wlo + (size_t)(oBase + row) * 384 + c0 + 8 * g; dp = Wl; }
      else if (plane == 2) { sp = xthi + (size_t)(nBase + row) * 384 + c0 + 8 * g; dp = Xh; }
      else                 { sp = xtlo + (size_t)(nBase + row) * 384 + c0 + 8 * g; dp = Xl; }
      uint4 v = *(const uint4*)sp;
      *(uint4*)&dp[row * 64 + 8 * (g ^ (row & 7))] = v;
    }
    __syncthreads();
#pragma unroll
    for (int s = 0; s < 2; ++s) {
      const int nrow = 16 * w + lq;
      const int g = 4 * s + lh;
      const int noff = nrow * 64 + 8 * (g ^ (nrow & 7));
      bf16x8 xh = *(const bf16x8*)&Xh[noff];
      bf16x8 xl = *(const bf16x8*)&Xl[noff];
#pragma unroll
      for (int f = 0; f < 4; ++f) {
        const int orow = 16 * f + lq;
        const int ooff = orow * 64 + 8 * (g ^ (orow & 7));
        bf16x8 wh_ = *(const bf16x8*)&Wh[ooff];
        bf16x8 wl_ = *(const bf16x8*)&Wl[ooff];
        acc[f] = __builtin_amdgcn_mfma_f32_16x16x32_bf16(wh_, xh, acc[f], 0, 0, 0);
        acc[f] = __builtin_amdgcn_mfma_f32_16x16x32_bf16(wh_, xl, acc[f], 0, 0, 0);
        acc[f] = __builtin_amdgcn_mfma_f32_16x16x32_bf16(wl_, xh, acc[f], 0, 0, 0);
      }
    }
  }

  const int t = oT % 3, head = oT / 3;
  ushort* pb = (ushort*)slot + 2 * (size_t)XT_U16 + (size_t)head * HEAD_U16;
  if (t == 0) {  // q: [n][64] hi/lo, scaled by log2e
    ushort* phi = pb;
    ushort* plo = pb + PLANE_U16;
    const int n = nBase + 16 * w + lq;
#pragma unroll
    for (int f = 0; f < 4; ++f) {
      ushort hi[4], lo[4];
#pragma unroll
      for (int r = 0; r < 4; ++r) {
        float v = acc[f][r] * LOG2E;
        hi[r] = f2bf(v);
        lo[r] = f2bf(v - bf2f(hi[r]));
      }
      uint2 uh, ul;
      uh.x = (uint)hi[0] | ((uint)hi[1] << 16); uh.y = (uint)hi[2] | ((uint)hi[3] << 16);
      ul.x = (uint)lo[0] | ((uint)lo[1] << 16); ul.y = (uint)lo[2] | ((uint)lo[3] << 16);
      const int d = 16 * f + 4 * lh;
      *(uint2*)&phi[(size_t)n * 64 + d] = uh;
      *(uint2*)&plo[(size_t)n * 64 + d] = ul;
    }
  } else if (t == 1) {  // k: swizzled tile planes 0 (hi) and 1 (lo)
    ushort* kv = pb + 2 * (size_t)PLANE_U16 + (size_t)nT * 12288;
    const int row = 16 * w + lq;  // key within tile
#pragma unroll
    for (int f = 0; f < 4; ++f) {
      ushort hi[4], lo[4];
#pragma unroll
      for (int r = 0; r < 4; ++r) {
        hi[r] = f2bf(acc[f][r]);
        lo[r] = f2bf(acc[f][r] - bf2f(hi[r]));
      }
      uint2 uh, ul;
      uh.x = (uint)hi[0] | ((uint)hi[1] << 16); uh.y = (uint)hi[2] | ((uint)hi[3] << 16);
      ul.x = (uint)lo[0] | ((uint)lo[1] << 16); ul.y = (uint)lo[2] | ((uint)lo[3] << 16);
      const int idx = row * 64 + 8 * ((2 * f + (lh >> 1)) ^ (row & 7)) + 4 * (lh & 1);
      *(uint2*)&kv[idx] = uh;
      *(uint2*)&kv[4096 + idx] = ul;
    }
  } else {  // v: swizzled tile plane 2, rows = d
    ushort* pv = pb + 2 * (size_t)PLANE_U16 + (size_t)nT * 12288 + 8192;
    const int col = 16 * w + lq;  // key within tile
    const int cg = col >> 3, cr = col & 7;
#pragma unroll
    for (int f = 0; f < 4; ++f)
#pragma unroll
      for (int r = 0; r < 4; ++r) {
        const int row = 16 * f + 4 * lh + r;
        pv[row * 64 + 8 * (cg ^ (row & 7)) + cr] = f2bf(acc[f][r]);
      }
  }
}

// ---------------------------------------------------------------------------
// Kernel B: MFMA flash attention.  global_load_lds staging of pre-swizzled
// 24 KB KV tiles; exp2-domain softmax with defer-max; cvt_pk P packing.
// ---------------------------------------------------------------------------
__global__ __launch_bounds__(256, 5) void attn_mfma_kernel(
    const ushort* __restrict__ wsu, float* __restrict__ out, int b0) {
  const int qt = blockIdx.x, h = blockIdx.y, bb = blockIdx.z;
  const int b = b0 + bb;
  const ushort* pb = wsu + 2 * (size_t)W_U16 + (size_t)bb * SLOT_U16 +
                     2 * (size_t)XT_U16 + (size_t)h * HEAD_U16;
  const ushort* qhiP = pb;
  const ushort* qloP = pb + PLANE_U16;
  const char* kvG = (const char*)(pb + 2 * (size_t)PLANE_U16);  // 36 x 24576 B
  const int n0 = qt * 64;

  __shared__ __align__(16) ushort KV[12288];   // Khi | Klo | Vh (pre-swizzled)
  __shared__ __align__(16) ushort Pw[4][16 * 64];

  const int tid = threadIdx.x;
  const int w = tid >> 6;
  const int l = tid & 63;
  const int lq = l & 15;
  const int lh = l >> 4;

  bf16x8 qh[2], ql[2];
  {
    const int qrow = n0 + 16 * w + lq;
    const ushort* qr = qhiP + (size_t)qrow * 64 + 8 * lh;
    const ushort* qr2 = qloP + (size_t)qrow * 64 + 8 * lh;
    qh[0] = *(const bf16x8*)(qr);
    qh[1] = *(const bf16x8*)(qr + 32);
    ql[0] = *(const bf16x8*)(qr2);
    ql[1] = *(const bf16x8*)(qr2 + 32);
  }

  f32x4 oac[4];
#pragma unroll
  for (int i = 0; i < 4; ++i) oac[i] = (f32x4){0.f, 0.f, 0.f, 0.f};
  float m_run = -3.0e38f, l_run = 0.f;

  const char* gsrc = kvG + w * 6144 + l * 16;
  char* ldst = (char*)&KV[0] + w * 6144;  // wave-uniform base; HW adds lane*16

  for (int mt = 0; mt < 36; ++mt) {
    __syncthreads();  // all waves done with previous tile
#pragma unroll
    for (int i = 0; i < 6; ++i) gload16(gsrc + i * 1024, ldst + i * 1024);
    gsrc += 24576;
    __syncthreads();  // drains vmcnt -> tile ready

    const ushort* Khi = &KV[0];
    const ushort* Klo = &KV[4096];
    const ushort* Vh = &KV[8192];

    f32x4 st[4];
#pragma unroll
    for (int f = 0; f < 4; ++f) st[f] = (f32x4){0.f, 0.f, 0.f, 0.f};
#pragma unroll
    for (int f = 0; f < 4; ++f) {
#pragma unroll
      for (int s = 0; s < 2; ++s) {
        const int row = 16 * f + lq;
        const int g = 4 * s + lh;
        const int off = row * 64 + 8 * (g ^ (row & 7));
        bf16x8 ah = *(const bf16x8*)&Khi[off];
        bf16x8 al = *(const bf16x8*)&Klo[off];
        st[f] = __builtin_amdgcn_mfma_f32_16x16x32_bf16(ah, qh[s], st[f], 0, 0, 0);
        st[f] = __builtin_amdgcn_mfma_f32_16x16x32_bf16(ah, ql[s], st[f], 0, 0, 0);
        st[f] = __builtin_amdgcn_mfma_f32_16x16x32_bf16(al, qh[s], st[f], 0, 0, 0);
      }
    }

    // Row max across this tile (lane holds 16 keys of one query; partners
    // at lane^16, lane^32 hold the rest).
    float tm = fmaxf(fmaxf(st[0][0], st[0][1]), fmaxf(st[0][2], st[0][3]));
#pragma unroll
    for (int f = 1; f < 4; ++f)
      tm = fmaxf(tm, fmaxf(fmaxf(st[f][0], st[f][1]), fmaxf(st[f][2], st[f][3])));
    tm = fmaxf(tm, __shfl_xor(tm, 16));
    tm = fmaxf(tm, __shfl_xor(tm, 32));

    // Defer-max: only rescale when the running max grew by > 8 (exp2 domain).
    if (__any(tm > m_run + 8.0f)) {
      const float mnew = fmaxf(m_run, tm);
      const float sc = exp2_fast(m_run - mnew);
#pragma unroll
      for (int fd = 0; fd < 4; ++fd) oac[fd] *= sc;
      l_run *= sc;
      m_run = mnew;
    }

    float ls = 0.f;
#pragma unroll
    for (int f = 0; f < 4; ++f)
#pragma unroll
      for (int r = 0; r < 4; ++r) {
        st[f][r] = exp2_fast(st[f][r] - m_run);
        ls += st[f][r];
      }
    ls += __shfl_xor(ls, 16);
    ls += __shfl_xor(ls, 32);
    l_run += ls;

    // Pack P to bf16 and bounce through per-wave swizzled LDS.
    ushort* pw = &Pw[w][0];
#pragma unroll
    for (int f = 0; f < 4; ++f) {
      uint2 uu;
      uu.x = cvt_pk_bf16(st[f][0], st[f][1]);
      uu.y = cvt_pk_bf16(st[f][2], st[f][3]);
      int ui = lq * 64 + 8 * ((2 * f + (lh >> 1)) ^ (lq & 7)) + 4 * (lh & 1);
      *(uint2*)&pw[ui] = uu;
    }
    bf16x8 pbf[2];
#pragma unroll
    for (int s = 0; s < 2; ++s)
      pbf[s] = *(const bf16x8*)&pw[lq * 64 + 8 * ((4 * s + lh) ^ (lq & 7))];

#pragma unroll
    for (int fd = 0; fd < 4; ++fd) {
#pragma unroll
      for (int s = 0; s < 2; ++s) {
        const int row = 16 * fd + lq;
        const int g = 4 * s + lh;
        bf16x8 av = *(const bf16x8*)&Vh[row * 64 + 8 * (g ^ (row & 7))];
        oac[fd] = __builtin_amdgcn_mfma_f32_16x16x32_bf16(av, pbf[s], oac[fd], 0, 0, 0);
      }
    }
  }

  const float inv = 1.f / l_run;
  const int ncol = n0 + 16 * w + lq;
#pragma unroll
  for (int fd = 0; fd < 4; ++fd)
#pragma unroll
    for (int r = 0; r < 4; ++r)
      out[((size_t)b * 384 + h * 64 + 16 * fd + 4 * lh + r) * NTOK + ncol] =
          oac[fd][r] * inv;
}

extern "C" void kernel_launch(void* const* d_in, const int* in_sizes, int n_in,
                              void* d_out, int out_size, void* d_ws,
                              size_t ws_size, hipStream_t stream) {
  const float* x = (const float*)d_in[0];
  const float* w = (const float*)d_in[1];
  float* out = (float*)d_out;
  ushort* wsu = (ushort*)d_ws;

  int nbFit = (int)((ws_size - WBYTES) / SLOT_BYTES);
  if (nbFit < 1) nbFit = 1;
  if (nbFit > NB) nbFit = NB;

  hipLaunchKernelGGL(prep_w_kernel, dim3(432), dim3(256), 0, stream, w, wsu);
  for (int b0 = 0; b0 < NB; b0 += nbFit) {
    int nb = NB - b0;
    if (nb > nbFit) nb = nbFit;
    hipLaunchKernelGGL(prep_x_kernel, dim3(48, 6, nb), dim3(256), 0, stream,
                       x, wsu, b0);
    hipLaunchKernelGGL(qkv_mfma_kernel, dim3(36, 18, nb), dim3(256), 0, stream,
                       wsu, b0);
    hipLaunchKernelGGL(attn_mfma_kernel, dim3(36, 6, nb), dim3(256), 0, stream,
                       wsu, out, b0);
  }
}